// Round 7
// baseline (20939.594 us; speedup 1.0000x reference)
//
// TrajectoryPredictor: 2-layer GRU enc (50 steps) -> autoregressive 2-layer GRU dec (30 steps) + fc head.
// Strategy: fp16 MFMA (16x16x32_f16) GEMM per layer-step, gate math fused in epilogue; state fp16 ping-pong.
// R2: LDS granule swizzle -> conflicts 0.   R3/R5: XCD-aware block swizzle.
// R7: BM=128 mt2, 3blk/CU: 127us L1, Mfma 36.  R8: BM=256 mt4, 2blk/CU: 119us, Mfma 38 (BEST).
// R9 FAILED: depth-1 prefetch + drain-0.  R10 FAILED: BK=32 ring (barrier/VALU bloat).
// R11 FAILED: A-in-regs + counted-vmcnt + no lockstep -> L2 thrash (FETCH 160/WRITE 102MB).
// R12 FAILED: (256,3) forced spill.  R13 FAILED: 8-wave counted phase pipeline (1 blk/CU, 2x barriers).
// LESSON: R8's lockstep __syncthreads cadence is load-bearing; only reduce WORK on its critical path.
// R14 (this): R8 skeleton EXACTLY (same barriers, same DMA B-staging, same grid/swizzle/writes),
//     but A's zero-reuse LDS round-trip removed: A loads global->VGPR (state layout is already
//     fragment-shaped), double-buffered one kc ahead (issued after barrier-1, covered by compute,
//     drained by barrier-2). LDS 44->12KB, per-CU LDS traffic 124->60KB per block-kc, 16 fewer
//     wave-ops/wave/kc. VGPR ~235 at (256,2), no spill. Controlled A/B vs R11: lockstep preserved.
// ws ~137 MB: 4x fp16 state (128MB) + packed weights (9MB) + biases.
#include <hip/hip_runtime.h>
#include <hip/hip_fp16.h>
#include <stdint.h>

typedef _Float16 h8 __attribute__((ext_vector_type(8)));
typedef float f4 __attribute__((ext_vector_type(4)));

#define DEV static __device__ __forceinline__

constexpr int BATCH  = 32768;
constexpr int HID    = 512;
constexpr int T_HIST = 50;
constexpr int FUT    = 30;
constexpr int BM = 256, BN = 32, BK = 64;

DEV void gl2lds16(const void* g, void* l) {
  __builtin_amdgcn_global_load_lds(
      (const __attribute__((address_space(1))) void*)g,
      (__attribute__((address_space(3))) void*)l,
      16, 0, 0);
}

DEV float sigm(float x)     { return 1.f / (1.f + __expf(-x)); }
DEV float tanhfast(float x) { return 1.f - 2.f / (__expf(2.f * x) + 1.f); }

// ---------------- utility: zero fill (graph-safe) ----------------
__global__ void zero_fill(float4* __restrict__ p, int n4) {
  int i = blockIdx.x * 256 + threadIdx.x;
  if (i < n4) p[i] = float4{0.f, 0.f, 0.f, 0.f};
}

// ---------------- weight/bias repack kernels ----------------
// target layout: (((nb*KC + kc)*3 + g)*32 + n)*64 + k, 16 col-blocks of 32 n, with 16B-granule
// XOR swizzle: stored granule k8s holds logical k8 = k8s ^ (n&7). source row = g*512 + nb*32 + n.
__global__ void pack_w(const float* __restrict__ Wa, const float* __restrict__ Wb,
                       _Float16* __restrict__ out, int KC) {
  int i = blockIdx.x * 256 + threadIdx.x;
  int total = 16 * KC * 3 * 32 * 64;
  if (i >= total) return;
  int k0  = i & 7;          // element within 16B granule
  int k8s = (i >> 3) & 7;   // stored granule index
  int n   = (i >> 6) & 31;
  int t   = i >> 11;        // (nb*KC + kc)*3 + g
  int g   = t % 3;
  int t2  = t / 3;
  int kc  = t2 % KC;
  int nb  = t2 / KC;
  int k8  = k8s ^ (n & 7);  // logical granule
  int row = g * 512 + nb * 32 + n;
  int kg  = kc * 64 + k8 * 8 + k0;
  float v = (kg < 512) ? Wa[(size_t)row * 512 + kg] : Wb[(size_t)row * 512 + kg - 512];
  out[i] = (_Float16)v;
}

// bias combine: [0]=b_ih_r+b_hh_r, [1]=b_ih_z+b_hh_z, [2]=b_ih_n, [3]=b_hh_n  (each 512)
__global__ void pack_bias(const float* __restrict__ bih, const float* __restrict__ bhh,
                          float* __restrict__ out) {
  int j = blockIdx.x * 256 + threadIdx.x;
  if (j >= 512) return;
  out[j]        = bih[j]        + bhh[j];
  out[512 + j]  = bih[512 + j]  + bhh[512 + j];
  out[1024 + j] = bih[1024 + j];
  out[1536 + j] = bhh[1024 + j];
}

// x-weights for layer0 (K=3): out[j*9 + g*3 + k] = W_ih[(g*512+j)*3 + k]
__global__ void pack_wx(const float* __restrict__ Wih, float* __restrict__ out) {
  int i = blockIdx.x * 256 + threadIdx.x;
  if (i >= 512 * 9) return;
  int j = i / 9, q = i % 9, g = q / 3, k = q % 3;
  out[i] = Wih[(size_t)(g * 512 + j) * 3 + k];
}

// ---------------- fused GRU layer-step GEMM: A-in-regs, B via DMA-LDS, R8 lockstep ----------------
// Block: 256m x 32n, 4 waves; wave w rows w*64..w*64+63 (mt4 x nt2, 128 acc f32 L1 / 96 L0).
// Per kc: stageB(kc) [3 gl2lds]; __syncthreads (drain); loadA(kc+1)->regs (covered by compute,
// drained by the closing __syncthreads); compute: 12 B ds_read_b128 + 48 MFMA (A from regs);
// __syncthreads. A-regs ping-pong Aa/Ab, statically named (no dynamic indexing).
// Grid: flat 2048; XCD-aware remap (16 col-blocks of a row-block land on one XCD, adjacent in time).
template <int KC, bool L0>
__launch_bounds__(256, 2)
__global__ void gru_step(const _Float16* __restrict__ Bp,     // packed weights [16][KC][3][32][64] (swizzled)
                         const _Float16* __restrict__ Alo,    // fp16 A, k<512 (L0: old state; L1: layer0 out)
                         const _Float16* __restrict__ Ahi,    // fp16 A, k>=512 (L1: old state)
                         _Float16* __restrict__ hnew16,       // fp16 new state
                         const float* __restrict__ bias,      // [4*512]
                         const float* __restrict__ Wx,        // [512*9] (L0) or null
                         const float* __restrict__ xin,       // x row base (L0) or null
                         int xstride) {
  __shared__ alignas(16) _Float16 sB[3 * BN * BK];    // 12KB, granule-swizzled (B only)

  const int tid  = threadIdx.x;
  const int wave = tid >> 6;
  const int lane = tid & 63;
  const int quad = lane >> 4;
  const int l15  = lane & 15;
  const int L  = blockIdx.x;              // 0..2047
  const int c  = L & 7;
  const int q  = L >> 3;                  // 0..255
  const int cb = q & 15;                  // 0..15
  const int rb = (c << 4) | (q >> 4);     // 0..127
  const int row0 = rb * BM;
  const int col0 = cb * BN;

  f4 acc_r[4][2]  = {};
  f4 acc_z[4][2]  = {};
  f4 acc_n0[4][2] = {};   // L1: i_n (kc<8); L0 unused (DCE'd)
  f4 acc_n1[4][2] = {};   // h_n

  const _Float16* Bblk = Bp + (size_t)cb * KC * (3 * BN * BK);

  // stage B K-tile kcs into LDS (12KB, 3 gl2lds/wave; swizzle pre-baked by pack_w)
  auto stageB = [&](int kcs) {
    const _Float16* Bsrc = Bblk + (size_t)kcs * (3 * BN * BK);
#pragma unroll
    for (int i = 0; i < 3; ++i) {
      int gb = wave * 192 + i * 64 + lane;
      gl2lds16(Bsrc + (size_t)gb * 8, &sB[(wave * 192 + i * 64) * 8]);  // HW adds lane*16B at dest
    }
  };
  // load A K-tile kcs into regs: tgt[mt*2+sk] = A[row0+wave*64+mt*16+l15][kb+sk*32+quad*8 ..+7]
  auto loadA = [&](int kcs, h8 (&tgt)[8]) {
    const _Float16* Asrc = (KC == 16 && kcs >= 8) ? Ahi : Alo;
    const int kb = (kcs & 7) * BK;
#pragma unroll
    for (int mt = 0; mt < 4; ++mt) {
      const _Float16* rp = Asrc + (size_t)(row0 + wave * 64 + mt * 16 + l15) * HID + kb + quad * 8;
      tgt[mt * 2 + 0] = *(const h8*)(rp);
      tgt[mt * 2 + 1] = *(const h8*)(rp + 32);
    }
  };
  // one K-tile of MFMAs: A from regs, B from LDS
  auto compute = [&](int s, const h8 (&A)[8]) {
#pragma unroll
    for (int sk = 0; sk < 2; ++sk) {
      const int sw = ((sk * 4 + quad) ^ (l15 & 7)) * 8;   // granule swizzle key
#pragma unroll
      for (int nt = 0; nt < 2; ++nt) {
        const int nrow = nt * 16 + l15;
        h8 br = *(const h8*)&sB[(0 * BN + nrow) * BK + sw];
        h8 bz = *(const h8*)&sB[(1 * BN + nrow) * BK + sw];
        h8 bn = *(const h8*)&sB[(2 * BN + nrow) * BK + sw];
#pragma unroll
        for (int mt = 0; mt < 4; ++mt) {
          acc_r[mt][nt] = __builtin_amdgcn_mfma_f32_16x16x32_f16(A[mt * 2 + sk], br, acc_r[mt][nt], 0, 0, 0);
          acc_z[mt][nt] = __builtin_amdgcn_mfma_f32_16x16x32_f16(A[mt * 2 + sk], bz, acc_z[mt][nt], 0, 0, 0);
          if (L0 || s >= 8)
            acc_n1[mt][nt] = __builtin_amdgcn_mfma_f32_16x16x32_f16(A[mt * 2 + sk], bn, acc_n1[mt][nt], 0, 0, 0);
          else
            acc_n0[mt][nt] = __builtin_amdgcn_mfma_f32_16x16x32_f16(A[mt * 2 + sk], bn, acc_n0[mt][nt], 0, 0, 0);
        }
      }
    }
  };

  h8 Aa[8], Ab[8];          // statically-named A ping-pong (rule: no dynamic reg-array indexing)
  loadA(0, Aa);             // prologue: A(0) in flight; drained by the first __syncthreads

  for (int s = 0; s < KC; s += 2) {   // KC is even (8 or 16)
    // ---- even kc s: compute with Aa, prefetch A(s+1) into Ab ----
    stageB(s);
    __syncthreads();                       // drains B(s) + A(s)
    if (s + 1 < KC) loadA(s + 1, Ab);      // issued under compute; drained by closing barrier
    compute(s, Aa);
    __syncthreads();                       // B buffer free; A(s+1) landed
    // ---- odd kc s+1: compute with Ab, prefetch A(s+2) into Aa ----
    stageB(s + 1);
    __syncthreads();
    if (s + 2 < KC) loadA(s + 2, Aa);
    compute(s + 1, Ab);
    __syncthreads();
  }

  // ---------------- fused epilogue: gates + state update ----------------
  const _Float16* hold16 = L0 ? Alo : Ahi;
  float bR[2], bZ[2], bI[2], bH[2];
  float wx[2][9];
#pragma unroll
  for (int nt = 0; nt < 2; ++nt) {
    int j = col0 + nt * 16 + l15;
    bR[nt] = bias[j];
    bZ[nt] = bias[512 + j];
    bI[nt] = bias[1024 + j];
    bH[nt] = bias[1536 + j];
    if constexpr (L0) {
#pragma unroll
      for (int q2 = 0; q2 < 9; ++q2) wx[nt][q2] = Wx[j * 9 + q2];
    }
  }
#pragma unroll
  for (int mt = 0; mt < 4; ++mt) {
    // xv scoped per-mt: keeps register peak down
    float xv[4][3];
    if constexpr (L0) {
#pragma unroll
      for (int r = 0; r < 4; ++r) {
        int b = row0 + wave * 64 + mt * 16 + quad * 4 + r;
        const float* xp = xin + (size_t)b * xstride;
        xv[r][0] = xp[0]; xv[r][1] = xp[1]; xv[r][2] = xp[2];
      }
    }
#pragma unroll
    for (int r = 0; r < 4; ++r) {
      int b = row0 + wave * 64 + mt * 16 + quad * 4 + r;   // C/D: row = quad*4+reg
#pragma unroll
      for (int nt = 0; nt < 2; ++nt) {
        int j = col0 + nt * 16 + l15;                       // C/D: col = lane&15
        size_t idx = (size_t)b * HID + j;
        float rr = acc_r[mt][nt][r] + bR[nt];
        float zz = acc_z[mt][nt][r] + bZ[nt];
        float hn = acc_n1[mt][nt][r] + bH[nt];
        float in_;
        if constexpr (L0) {
          const float* w = wx[nt];
          rr += xv[r][0] * w[0] + xv[r][1] * w[1] + xv[r][2] * w[2];
          zz += xv[r][0] * w[3] + xv[r][1] * w[4] + xv[r][2] * w[5];
          in_ = bI[nt] + xv[r][0] * w[6] + xv[r][1] * w[7] + xv[r][2] * w[8];
        } else {
          in_ = acc_n0[mt][nt][r] + bI[nt];
        }
        float rg = sigm(rr);
        float zg = sigm(zz);
        float ng = tanhfast(in_ + rg * hn);
        float hp = (float)hold16[idx];
        float hv = (1.f - zg) * ng + zg * hp;
        hnew16[idx] = (_Float16)hv;
      }
    }
  }
}

// ---------------- fc head: pred[b,d] = h[b,:] . fcW[d,:] + fcb[d] ----------------
__global__ __launch_bounds__(256) void fc_kernel(const _Float16* __restrict__ h,
                                                 const float* __restrict__ W,
                                                 const float* __restrict__ bfc,
                                                 float* __restrict__ out) {  // out = d_out + t*3
  int wave = threadIdx.x >> 6, lane = threadIdx.x & 63;
  int b = blockIdx.x * 4 + wave;
  const h8* hp = (const h8*)(h + (size_t)b * 512);
  h8 a0 = hp[lane];
  float s[3];
#pragma unroll
  for (int d = 0; d < 3; ++d) {
    const float4* wp = (const float4*)(W + d * 512);
    float4 w0 = wp[lane * 2], w1 = wp[lane * 2 + 1];
    s[d] = (float)a0[0] * w0.x + (float)a0[1] * w0.y + (float)a0[2] * w0.z + (float)a0[3] * w0.w
         + (float)a0[4] * w1.x + (float)a0[5] * w1.y + (float)a0[6] * w1.z + (float)a0[7] * w1.w;
  }
#pragma unroll
  for (int d = 0; d < 3; ++d)
#pragma unroll
    for (int off = 32; off > 0; off >>= 1) s[d] += __shfl_xor(s[d], off, 64);
  if (lane == 0) {
    out[(size_t)b * 90 + 0] = s[0] + bfc[0];
    out[(size_t)b * 90 + 1] = s[1] + bfc[1];
    out[(size_t)b * 90 + 2] = s[2] + bfc[2];
  }
}

extern "C" void kernel_launch(void* const* d_in, const int* in_sizes, int n_in,
                              void* d_out, int out_size, void* d_ws, size_t ws_size,
                              hipStream_t stream) {
  (void)in_sizes; (void)n_in; (void)out_size; (void)ws_size;
  const float* x_input = (const float*)d_in[0];
  const float* eWih0 = (const float*)d_in[2];
  const float* eWhh0 = (const float*)d_in[3];
  const float* ebih0 = (const float*)d_in[4];
  const float* ebhh0 = (const float*)d_in[5];
  const float* eWih1 = (const float*)d_in[6];
  const float* eWhh1 = (const float*)d_in[7];
  const float* ebih1 = (const float*)d_in[8];
  const float* ebhh1 = (const float*)d_in[9];
  const float* dWih0 = (const float*)d_in[10];
  const float* dWhh0 = (const float*)d_in[11];
  const float* dbih0 = (const float*)d_in[12];
  const float* dbhh0 = (const float*)d_in[13];
  const float* dWih1 = (const float*)d_in[14];
  const float* dWhh1 = (const float*)d_in[15];
  const float* dbih1 = (const float*)d_in[16];
  const float* dbhh1 = (const float*)d_in[17];
  const float* fcW   = (const float*)d_in[18];
  const float* fcb   = (const float*)d_in[19];
  float* out = (float*)d_out;

  char* ws = (char*)d_ws;
  const size_t S16 = (size_t)BATCH * HID * 2;   // 32MB
  _Float16* h0h[2] = {(_Float16*)(ws),            (_Float16*)(ws + S16)};
  _Float16* h1h[2] = {(_Float16*)(ws + 2 * S16),  (_Float16*)(ws + 3 * S16)};
  char* p = ws + 4 * S16;                        // 128MB
  const size_t W8  = (size_t)16 * 8  * 3 * 32 * 64 * 2;  // 1.5MB (KC=8)
  const size_t W16 = (size_t)16 * 16 * 3 * 32 * 64 * 2;  // 3MB (KC=16)
  _Float16* pkE0 = (_Float16*)p; p += W8;
  _Float16* pkE1 = (_Float16*)p; p += W16;
  _Float16* pkD0 = (_Float16*)p; p += W8;
  _Float16* pkD1 = (_Float16*)p; p += W16;
  float* bE0 = (float*)p; p += 2048 * 4;
  float* bE1 = (float*)p; p += 2048 * 4;
  float* bD0 = (float*)p; p += 2048 * 4;
  float* bD1 = (float*)p; p += 2048 * 4;
  float* wxE = (float*)p; p += 512 * 9 * 4;
  float* wxD = (float*)p; p += 512 * 9 * 4;
  // total ws usage: 128MB + ~9.1MB

  // repack weights/biases (every call; ws is re-poisoned by harness)
  pack_w<<<dim3(3072), 256, 0, stream>>>(eWhh0, eWhh0, pkE0, 8);
  pack_w<<<dim3(6144), 256, 0, stream>>>(eWih1, eWhh1, pkE1, 16);
  pack_w<<<dim3(3072), 256, 0, stream>>>(dWhh0, dWhh0, pkD0, 8);
  pack_w<<<dim3(6144), 256, 0, stream>>>(dWih1, dWhh1, pkD1, 16);
  pack_bias<<<2, 256, 0, stream>>>(ebih0, ebhh0, bE0);
  pack_bias<<<2, 256, 0, stream>>>(ebih1, ebhh1, bE1);
  pack_bias<<<2, 256, 0, stream>>>(dbih0, dbhh0, bD0);
  pack_bias<<<2, 256, 0, stream>>>(dbih1, dbhh1, bD1);
  pack_wx<<<18, 256, 0, stream>>>(eWih0, wxE);
  pack_wx<<<18, 256, 0, stream>>>(dWih0, wxD);

  // zero-init fp16 states (ping index 0)
  {
    int n4 = (int)(S16 / 16);
    zero_fill<<<(n4 + 255) / 256, 256, 0, stream>>>((float4*)h0h[0], n4);
    zero_fill<<<(n4 + 255) / 256, 256, 0, stream>>>((float4*)h1h[0], n4);
  }

  dim3 grid(2048), blk(256);
  int p0 = 0, p1 = 0;
  // encoder
  for (int t = 0; t < T_HIST; ++t) {
    gru_step<8, true><<<grid, blk, 0, stream>>>(pkE0, h0h[p0], nullptr,
                                                h0h[1 - p0], bE0, wxE,
                                                x_input + (size_t)t * 3, 150);
    p0 ^= 1;
    gru_step<16, false><<<grid, blk, 0, stream>>>(pkE1, h0h[p0], h1h[p1],
                                                  h1h[1 - p1], bE1, nullptr, nullptr, 0);
    p1 ^= 1;
  }
  // autoregressive decoder
  for (int t = 0; t < FUT; ++t) {
    const float* xp; int xs;
    if (t == 0) { xp = x_input + (size_t)49 * 3; xs = 150; }
    else        { xp = out + (size_t)(t - 1) * 3; xs = 90; }
    gru_step<8, true><<<grid, blk, 0, stream>>>(pkD0, h0h[p0], nullptr,
                                                h0h[1 - p0], bD0, wxD, xp, xs);
    p0 ^= 1;
    gru_step<16, false><<<grid, blk, 0, stream>>>(pkD1, h0h[p0], h1h[p1],
                                                  h1h[1 - p1], bD1, nullptr, nullptr, 0);
    p1 ^= 1;
    fc_kernel<<<8192, 256, 0, stream>>>(h1h[p1], fcW, fcb, out + (size_t)t * 3);
  }
}

// Round 8
// 19804.158 us; speedup vs baseline: 1.0573x; 1.0573x over previous
//
// TrajectoryPredictor: 2-layer GRU enc (50 steps) -> autoregressive 2-layer GRU dec (30 steps) + fc head.
// Strategy: fp16 MFMA (16x16x32_f16) GEMM per layer-step, gate math fused in epilogue; state fp16 ping-pong.
// R2: LDS granule swizzle -> conflicts 0.   R3/R5: XCD-aware block swizzle.
// R7: BM=128 mt2: 127us L1, Mfma 36.  R8: BM=256 mt4, 2blk/CU, 2x __syncthreads/kc: 119us, Mfma 38 (BEST).
// R9 FAILED: drain-0 depth-1.  R10 FAILED: BK=32 ring (4x barriers).  R11 FAILED: lost write-merge
//     lockstep (WRITE 102MB).  R12 FAILED: (256,3) spill.  R13 FAILED: 1 blk/CU + 4 barriers/kc.
// R14: A-in-regs under __syncthreads: counters CLEAN (FETCH 82MB, WRITE exact, no spill) but 184us --
//     __syncthreads drains vmcnt(0), so B-DMA drain (uncovered) + A-load drain (230cyc cover) both
//     exposed every kc. LESSON: A-in-regs traffic cut is right; needs prefetch that SURVIVES a barrier.
// R15 (this): A-in-regs + B-only LDS ring-3 (36KB -> 2 blk/CU) + ONE raw s_barrier per kc + counted
//     vmcnt(11): tile-s loads (3 B-DMA + 8 A-loads, issued one kc earlier, ~500cyc cover) are waited;
//     tile-s+1 issues stay in flight across the barrier. 48 MFMA/barrier, no drain in steady state.
//     Race-freedom: stage(s+1)->slot (s+1)%3 vs its last readers compute(s-2) separated by barrier(s-1);
//     per-wave vmcnt + barrier(s) publishes all waves' B before compute(s).
// ws ~137 MB: 4x fp16 state (128MB) + packed weights (9MB) + biases.
#include <hip/hip_runtime.h>
#include <hip/hip_fp16.h>
#include <stdint.h>

typedef _Float16 h8 __attribute__((ext_vector_type(8)));
typedef float f4 __attribute__((ext_vector_type(4)));

#define DEV static __device__ __forceinline__

constexpr int BATCH  = 32768;
constexpr int HID    = 512;
constexpr int T_HIST = 50;
constexpr int FUT    = 30;
constexpr int BM = 256, BN = 32, BK = 64;

DEV void gl2lds16(const void* g, void* l) {
  __builtin_amdgcn_global_load_lds(
      (const __attribute__((address_space(1))) void*)g,
      (__attribute__((address_space(3))) void*)l,
      16, 0, 0);
}

DEV float sigm(float x)     { return 1.f / (1.f + __expf(-x)); }
DEV float tanhfast(float x) { return 1.f - 2.f / (__expf(2.f * x) + 1.f); }

// ---------------- utility: zero fill (graph-safe) ----------------
__global__ void zero_fill(float4* __restrict__ p, int n4) {
  int i = blockIdx.x * 256 + threadIdx.x;
  if (i < n4) p[i] = float4{0.f, 0.f, 0.f, 0.f};
}

// ---------------- weight/bias repack kernels ----------------
// target layout: (((nb*KC + kc)*3 + g)*32 + n)*64 + k, 16 col-blocks of 32 n, with 16B-granule
// XOR swizzle: stored granule k8s holds logical k8 = k8s ^ (n&7). source row = g*512 + nb*32 + n.
__global__ void pack_w(const float* __restrict__ Wa, const float* __restrict__ Wb,
                       _Float16* __restrict__ out, int KC) {
  int i = blockIdx.x * 256 + threadIdx.x;
  int total = 16 * KC * 3 * 32 * 64;
  if (i >= total) return;
  int k0  = i & 7;          // element within 16B granule
  int k8s = (i >> 3) & 7;   // stored granule index
  int n   = (i >> 6) & 31;
  int t   = i >> 11;        // (nb*KC + kc)*3 + g
  int g   = t % 3;
  int t2  = t / 3;
  int kc  = t2 % KC;
  int nb  = t2 / KC;
  int k8  = k8s ^ (n & 7);  // logical granule
  int row = g * 512 + nb * 32 + n;
  int kg  = kc * 64 + k8 * 8 + k0;
  float v = (kg < 512) ? Wa[(size_t)row * 512 + kg] : Wb[(size_t)row * 512 + kg - 512];
  out[i] = (_Float16)v;
}

// bias combine: [0]=b_ih_r+b_hh_r, [1]=b_ih_z+b_hh_z, [2]=b_ih_n, [3]=b_hh_n  (each 512)
__global__ void pack_bias(const float* __restrict__ bih, const float* __restrict__ bhh,
                          float* __restrict__ out) {
  int j = blockIdx.x * 256 + threadIdx.x;
  if (j >= 512) return;
  out[j]        = bih[j]        + bhh[j];
  out[512 + j]  = bih[512 + j]  + bhh[512 + j];
  out[1024 + j] = bih[1024 + j];
  out[1536 + j] = bhh[1024 + j];
}

// x-weights for layer0 (K=3): out[j*9 + g*3 + k] = W_ih[(g*512+j)*3 + k]
__global__ void pack_wx(const float* __restrict__ Wih, float* __restrict__ out) {
  int i = blockIdx.x * 256 + threadIdx.x;
  if (i >= 512 * 9) return;
  int j = i / 9, q = i % 9, g = q / 3, k = q % 3;
  out[i] = Wih[(size_t)(g * 512 + j) * 3 + k];
}

// ---------------- fused GRU layer-step GEMM: A-in-regs + B ring-3 + counted vmcnt ----------------
// Block: 256m x 32n, 4 waves; wave w rows w*64..w*64+63 (mt4 x nt2, 128 acc f32 L1 / 96 L0).
// Per kc: issue stage B(s+1) [3 gl2lds] + loadA(s+1)->regs [8 dwordx4]; s_waitcnt vmcnt(11)
// (tile-s loads, issued one kc earlier, landed; tile-s+1 in flight); ONE raw s_barrier;
// compute: 12 B ds_read_b128 + 48 MFMA (A from regs). No vmem drain in the loop body.
// Grid: flat 2048; XCD-aware remap (16 col-blocks of a row-block land on one XCD, adjacent in time).
template <int KC, bool L0>
__launch_bounds__(256, 2)
__global__ void gru_step(const _Float16* __restrict__ Bp,     // packed weights [16][KC][3][32][64] (swizzled)
                         const _Float16* __restrict__ Alo,    // fp16 A, k<512 (L0: old state; L1: layer0 out)
                         const _Float16* __restrict__ Ahi,    // fp16 A, k>=512 (L1: old state)
                         _Float16* __restrict__ hnew16,       // fp16 new state
                         const float* __restrict__ bias,      // [4*512]
                         const float* __restrict__ Wx,        // [512*9] (L0) or null
                         const float* __restrict__ xin,       // x row base (L0) or null
                         int xstride) {
  __shared__ alignas(16) _Float16 sB3[3][3 * BN * BK];    // 3 x 12KB ring (B only)

  const int tid  = threadIdx.x;
  const int wave = tid >> 6;
  const int lane = tid & 63;
  const int quad = lane >> 4;
  const int l15  = lane & 15;
  const int L  = blockIdx.x;              // 0..2047
  const int c  = L & 7;
  const int q  = L >> 3;                  // 0..255
  const int cb = q & 15;                  // 0..15
  const int rb = (c << 4) | (q >> 4);     // 0..127
  const int row0 = rb * BM;
  const int col0 = cb * BN;

  f4 acc_r[4][2]  = {};
  f4 acc_z[4][2]  = {};
  f4 acc_n0[4][2] = {};   // L1: i_n (kc<8); L0 unused (DCE'd)
  f4 acc_n1[4][2] = {};   // h_n

  const _Float16* Bblk = Bp + (size_t)cb * KC * (3 * BN * BK);

  // stage B K-tile kcs into ring slot dst (12KB, 3 gl2lds/wave; swizzle pre-baked by pack_w)
  auto stageB = [&](int kcs, _Float16* dst) {
    const _Float16* Bsrc = Bblk + (size_t)kcs * (3 * BN * BK);
#pragma unroll
    for (int i = 0; i < 3; ++i) {
      int off = wave * 192 + i * 64;
      gl2lds16(Bsrc + (size_t)(off + lane) * 8, dst + (size_t)off * 8);  // HW adds lane*16B at dest
    }
  };
  // load A K-tile kcs into regs: tgt[mt*2+sk] = A[row0+wave*64+mt*16+l15][kb+sk*32+quad*8 ..+7]
  auto loadA = [&](int kcs, h8 (&tgt)[8]) {
    const _Float16* Asrc = (KC == 16 && kcs >= 8) ? Ahi : Alo;
    const int kb = (kcs & 7) * BK;
#pragma unroll
    for (int mt = 0; mt < 4; ++mt) {
      const _Float16* rp = Asrc + (size_t)(row0 + wave * 64 + mt * 16 + l15) * HID + kb + quad * 8;
      tgt[mt * 2 + 0] = *(const h8*)(rp);
      tgt[mt * 2 + 1] = *(const h8*)(rp + 32);
    }
  };
  // one K-tile of MFMAs: A from regs, B from ring slot
  auto compute = [&](int s, const _Float16* sBc, const h8 (&A)[8]) {
#pragma unroll
    for (int sk = 0; sk < 2; ++sk) {
      const int sw = ((sk * 4 + quad) ^ (l15 & 7)) * 8;   // granule swizzle key
#pragma unroll
      for (int nt = 0; nt < 2; ++nt) {
        const int nrow = nt * 16 + l15;
        h8 br = *(const h8*)&sBc[(0 * BN + nrow) * BK + sw];
        h8 bz = *(const h8*)&sBc[(1 * BN + nrow) * BK + sw];
        h8 bn = *(const h8*)&sBc[(2 * BN + nrow) * BK + sw];
#pragma unroll
        for (int mt = 0; mt < 4; ++mt) {
          acc_r[mt][nt] = __builtin_amdgcn_mfma_f32_16x16x32_f16(A[mt * 2 + sk], br, acc_r[mt][nt], 0, 0, 0);
          acc_z[mt][nt] = __builtin_amdgcn_mfma_f32_16x16x32_f16(A[mt * 2 + sk], bz, acc_z[mt][nt], 0, 0, 0);
          if (L0 || s >= 8)
            acc_n1[mt][nt] = __builtin_amdgcn_mfma_f32_16x16x32_f16(A[mt * 2 + sk], bn, acc_n1[mt][nt], 0, 0, 0);
          else
            acc_n0[mt][nt] = __builtin_amdgcn_mfma_f32_16x16x32_f16(A[mt * 2 + sk], bn, acc_n0[mt][nt], 0, 0, 0);
        }
      }
    }
  };

  h8 Aa[8], Ab[8];                 // statically-named A ping-pong (rule: no dynamic reg indexing)
  stageB(0, sB3[0]); loadA(0, Aa); // prologue: tile 0 in flight (11 vmem ops)

  int cs = 0;                      // ring slot of tile s
  for (int s = 0; s < KC; s += 2) {   // KC even (8 or 16)
    const int s1 = (cs == 2) ? 0 : cs + 1;
    const int s2 = (s1 == 2) ? 0 : s1 + 1;
    // ---- even kc s: prefetch tile s+1 -> slot s1 / regs Ab; compute tile s from slot cs / Aa ----
    stageB(s + 1, sB3[s1]); loadA(s + 1, Ab);
    asm volatile("s_waitcnt vmcnt(11)" ::: "memory");   // tile-s loads landed; s+1 stays in flight
    __builtin_amdgcn_s_barrier();                        // all waves' B(s) visible; slot s2 free
    __builtin_amdgcn_sched_barrier(0);                   // no ds_read hoisted above the barrier
    compute(s, sB3[cs], Aa);
    // ---- odd kc s+1: prefetch tile s+2 -> slot s2 / regs Aa; compute tile s+1 from slot s1 / Ab ----
    if (s + 2 < KC) {
      stageB(s + 2, sB3[s2]); loadA(s + 2, Aa);
      asm volatile("s_waitcnt vmcnt(11)" ::: "memory");
    } else {
      asm volatile("s_waitcnt vmcnt(0)" ::: "memory");   // tail: tile KC-1 loads had a full kc to land
    }
    __builtin_amdgcn_s_barrier();
    __builtin_amdgcn_sched_barrier(0);
    compute(s + 1, sB3[s1], Ab);
    cs = s2;
  }

  // ---------------- fused epilogue: gates + state update ----------------
  const _Float16* hold16 = L0 ? Alo : Ahi;
  float bR[2], bZ[2], bI[2], bH[2];
  float wx[2][9];
#pragma unroll
  for (int nt = 0; nt < 2; ++nt) {
    int j = col0 + nt * 16 + l15;
    bR[nt] = bias[j];
    bZ[nt] = bias[512 + j];
    bI[nt] = bias[1024 + j];
    bH[nt] = bias[1536 + j];
    if constexpr (L0) {
#pragma unroll
      for (int q2 = 0; q2 < 9; ++q2) wx[nt][q2] = Wx[j * 9 + q2];
    }
  }
#pragma unroll
  for (int mt = 0; mt < 4; ++mt) {
    // xv scoped per-mt: keeps register peak down
    float xv[4][3];
    if constexpr (L0) {
#pragma unroll
      for (int r = 0; r < 4; ++r) {
        int b = row0 + wave * 64 + mt * 16 + quad * 4 + r;
        const float* xp = xin + (size_t)b * xstride;
        xv[r][0] = xp[0]; xv[r][1] = xp[1]; xv[r][2] = xp[2];
      }
    }
#pragma unroll
    for (int r = 0; r < 4; ++r) {
      int b = row0 + wave * 64 + mt * 16 + quad * 4 + r;   // C/D: row = quad*4+reg
#pragma unroll
      for (int nt = 0; nt < 2; ++nt) {
        int j = col0 + nt * 16 + l15;                       // C/D: col = lane&15
        size_t idx = (size_t)b * HID + j;
        float rr = acc_r[mt][nt][r] + bR[nt];
        float zz = acc_z[mt][nt][r] + bZ[nt];
        float hn = acc_n1[mt][nt][r] + bH[nt];
        float in_;
        if constexpr (L0) {
          const float* w = wx[nt];
          rr += xv[r][0] * w[0] + xv[r][1] * w[1] + xv[r][2] * w[2];
          zz += xv[r][0] * w[3] + xv[r][1] * w[4] + xv[r][2] * w[5];
          in_ = bI[nt] + xv[r][0] * w[6] + xv[r][1] * w[7] + xv[r][2] * w[8];
        } else {
          in_ = acc_n0[mt][nt][r] + bI[nt];
        }
        float rg = sigm(rr);
        float zg = sigm(zz);
        float ng = tanhfast(in_ + rg * hn);
        float hp = (float)hold16[idx];
        float hv = (1.f - zg) * ng + zg * hp;
        hnew16[idx] = (_Float16)hv;
      }
    }
  }
}

// ---------------- fc head: pred[b,d] = h[b,:] . fcW[d,:] + fcb[d] ----------------
__global__ __launch_bounds__(256) void fc_kernel(const _Float16* __restrict__ h,
                                                 const float* __restrict__ W,
                                                 const float* __restrict__ bfc,
                                                 float* __restrict__ out) {  // out = d_out + t*3
  int wave = threadIdx.x >> 6, lane = threadIdx.x & 63;
  int b = blockIdx.x * 4 + wave;
  const h8* hp = (const h8*)(h + (size_t)b * 512);
  h8 a0 = hp[lane];
  float s[3];
#pragma unroll
  for (int d = 0; d < 3; ++d) {
    const float4* wp = (const float4*)(W + d * 512);
    float4 w0 = wp[lane * 2], w1 = wp[lane * 2 + 1];
    s[d] = (float)a0[0] * w0.x + (float)a0[1] * w0.y + (float)a0[2] * w0.z + (float)a0[3] * w0.w
         + (float)a0[4] * w1.x + (float)a0[5] * w1.y + (float)a0[6] * w1.z + (float)a0[7] * w1.w;
  }
#pragma unroll
  for (int d = 0; d < 3; ++d)
#pragma unroll
    for (int off = 32; off > 0; off >>= 1) s[d] += __shfl_xor(s[d], off, 64);
  if (lane == 0) {
    out[(size_t)b * 90 + 0] = s[0] + bfc[0];
    out[(size_t)b * 90 + 1] = s[1] + bfc[1];
    out[(size_t)b * 90 + 2] = s[2] + bfc[2];
  }
}

extern "C" void kernel_launch(void* const* d_in, const int* in_sizes, int n_in,
                              void* d_out, int out_size, void* d_ws, size_t ws_size,
                              hipStream_t stream) {
  (void)in_sizes; (void)n_in; (void)out_size; (void)ws_size;
  const float* x_input = (const float*)d_in[0];
  const float* eWih0 = (const float*)d_in[2];
  const float* eWhh0 = (const float*)d_in[3];
  const float* ebih0 = (const float*)d_in[4];
  const float* ebhh0 = (const float*)d_in[5];
  const float* eWih1 = (const float*)d_in[6];
  const float* eWhh1 = (const float*)d_in[7];
  const float* ebih1 = (const float*)d_in[8];
  const float* ebhh1 = (const float*)d_in[9];
  const float* dWih0 = (const float*)d_in[10];
  const float* dWhh0 = (const float*)d_in[11];
  const float* dbih0 = (const float*)d_in[12];
  const float* dbhh0 = (const float*)d_in[13];
  const float* dWih1 = (const float*)d_in[14];
  const float* dWhh1 = (const float*)d_in[15];
  const float* dbih1 = (const float*)d_in[16];
  const float* dbhh1 = (const float*)d_in[17];
  const float* fcW   = (const float*)d_in[18];
  const float* fcb   = (const float*)d_in[19];
  float* out = (float*)d_out;

  char* ws = (char*)d_ws;
  const size_t S16 = (size_t)BATCH * HID * 2;   // 32MB
  _Float16* h0h[2] = {(_Float16*)(ws),            (_Float16*)(ws + S16)};
  _Float16* h1h[2] = {(_Float16*)(ws + 2 * S16),  (_Float16*)(ws + 3 * S16)};
  char* p = ws + 4 * S16;                        // 128MB
  const size_t W8  = (size_t)16 * 8  * 3 * 32 * 64 * 2;  // 1.5MB (KC=8)
  const size_t W16 = (size_t)16 * 16 * 3 * 32 * 64 * 2;  // 3MB (KC=16)
  _Float16* pkE0 = (_Float16*)p; p += W8;
  _Float16* pkE1 = (_Float16*)p; p += W16;
  _Float16* pkD0 = (_Float16*)p; p += W8;
  _Float16* pkD1 = (_Float16*)p; p += W16;
  float* bE0 = (float*)p; p += 2048 * 4;
  float* bE1 = (float*)p; p += 2048 * 4;
  float* bD0 = (float*)p; p += 2048 * 4;
  float* bD1 = (float*)p; p += 2048 * 4;
  float* wxE = (float*)p; p += 512 * 9 * 4;
  float* wxD = (float*)p; p += 512 * 9 * 4;
  // total ws usage: 128MB + ~9.1MB

  // repack weights/biases (every call; ws is re-poisoned by harness)
  pack_w<<<dim3(3072), 256, 0, stream>>>(eWhh0, eWhh0, pkE0, 8);
  pack_w<<<dim3(6144), 256, 0, stream>>>(eWih1, eWhh1, pkE1, 16);
  pack_w<<<dim3(3072), 256, 0, stream>>>(dWhh0, dWhh0, pkD0, 8);
  pack_w<<<dim3(6144), 256, 0, stream>>>(dWih1, dWhh1, pkD1, 16);
  pack_bias<<<2, 256, 0, stream>>>(ebih0, ebhh0, bE0);
  pack_bias<<<2, 256, 0, stream>>>(ebih1, ebhh1, bE1);
  pack_bias<<<2, 256, 0, stream>>>(dbih0, dbhh0, bD0);
  pack_bias<<<2, 256, 0, stream>>>(dbih1, dbhh1, bD1);
  pack_wx<<<18, 256, 0, stream>>>(eWih0, wxE);
  pack_wx<<<18, 256, 0, stream>>>(dWih0, wxD);

  // zero-init fp16 states (ping index 0)
  {
    int n4 = (int)(S16 / 16);
    zero_fill<<<(n4 + 255) / 256, 256, 0, stream>>>((float4*)h0h[0], n4);
    zero_fill<<<(n4 + 255) / 256, 256, 0, stream>>>((float4*)h1h[0], n4);
  }

  dim3 grid(2048), blk(256);
  int p0 = 0, p1 = 0;
  // encoder
  for (int t = 0; t < T_HIST; ++t) {
    gru_step<8, true><<<grid, blk, 0, stream>>>(pkE0, h0h[p0], nullptr,
                                                h0h[1 - p0], bE0, wxE,
                                                x_input + (size_t)t * 3, 150);
    p0 ^= 1;
    gru_step<16, false><<<grid, blk, 0, stream>>>(pkE1, h0h[p0], h1h[p1],
                                                  h1h[1 - p1], bE1, nullptr, nullptr, 0);
    p1 ^= 1;
  }
  // autoregressive decoder
  for (int t = 0; t < FUT; ++t) {
    const float* xp; int xs;
    if (t == 0) { xp = x_input + (size_t)49 * 3; xs = 150; }
    else        { xp = out + (size_t)(t - 1) * 3; xs = 90; }
    gru_step<8, true><<<grid, blk, 0, stream>>>(pkD0, h0h[p0], nullptr,
                                                h0h[1 - p0], bD0, wxD, xp, xs);
    p0 ^= 1;
    gru_step<16, false><<<grid, blk, 0, stream>>>(pkD1, h0h[p0], h1h[p1],
                                                  h1h[1 - p1], bD1, nullptr, nullptr, 0);
    p1 ^= 1;
    fc_kernel<<<8192, 256, 0, stream>>>(h1h[p1], fcW, fcb, out + (size_t)t * 3);
  }
}

// Round 9
// 16289.616 us; speedup vs baseline: 1.2855x; 1.2158x over previous
//
// TrajectoryPredictor: 2-layer GRU enc (50 steps) -> autoregressive 2-layer GRU dec (30 steps) + fc head.
// Strategy: fp16 MFMA (16x16x32_f16) GEMM per layer-step, gate math fused in epilogue; state fp16 ping-pong.
// R2: LDS granule swizzle -> conflicts 0.   R3/R5: XCD-aware block swizzle.
// R8 (BEST 15.1ms): BM=256 mt4, 2blk/CU, __syncthreads lockstep: L1 119us, Mfma 38.
// R9/R10/R12/R13 FAILED (drain-0 / barrier bloat / spill / 1blk-CU).
// R11+R15 FAILED vs R14 CLEAN -> isolated variable: epilogue writes 64B per 128B line, other half
//     owned by the NEIGHBOR cb block. Lockstep (R14) -> L2 merges (WRITE exact); pipelined (R11/R15)
//     -> drift -> half-dirty evictions -> RMW (WRITE 98-102MB, FETCH +70MB, L2 thrash, Mfma 25).
// R16 (this): keep R15's pipeline (A-in-regs, B ring-3 36KB 2blk/CU, ONE raw s_barrier/kc,
//     vmcnt(11) one-kc cover, no drains); fix the writes BY LAYOUT: state stored as
//     [16 chunks][BATCH][32 cols] fp16 -> each block writes chunk cb as a contiguous 256x64B
//     region (consecutive ROWS of the same block share each 128B line -> full-line under any
//     drift). A-loads become 16-consecutive-row x 64B reads (better coalesced). fc re-addressed.
// ws ~137 MB: 4x fp16 state (128MB) + packed weights (9MB) + biases.
#include <hip/hip_runtime.h>
#include <hip/hip_fp16.h>
#include <stdint.h>

typedef _Float16 h8 __attribute__((ext_vector_type(8)));
typedef float f4 __attribute__((ext_vector_type(4)));

#define DEV static __device__ __forceinline__

constexpr int BATCH  = 32768;
constexpr int HID    = 512;
constexpr int T_HIST = 50;
constexpr int FUT    = 30;
constexpr int BM = 256, BN = 32, BK = 64;
// state layout: [chunk=col/32][b][col%32] fp16  ->  elem(ch,b,c) = (ch*BATCH + b)*32 + c

DEV void gl2lds16(const void* g, void* l) {
  __builtin_amdgcn_global_load_lds(
      (const __attribute__((address_space(1))) void*)g,
      (__attribute__((address_space(3))) void*)l,
      16, 0, 0);
}

DEV float sigm(float x)     { return 1.f / (1.f + __expf(-x)); }
DEV float tanhfast(float x) { return 1.f - 2.f / (__expf(2.f * x) + 1.f); }

// ---------------- utility: zero fill (graph-safe) ----------------
__global__ void zero_fill(float4* __restrict__ p, int n4) {
  int i = blockIdx.x * 256 + threadIdx.x;
  if (i < n4) p[i] = float4{0.f, 0.f, 0.f, 0.f};
}

// ---------------- weight/bias repack kernels ----------------
// target layout: (((nb*KC + kc)*3 + g)*32 + n)*64 + k, 16 col-blocks of 32 n, with 16B-granule
// XOR swizzle: stored granule k8s holds logical k8 = k8s ^ (n&7). source row = g*512 + nb*32 + n.
__global__ void pack_w(const float* __restrict__ Wa, const float* __restrict__ Wb,
                       _Float16* __restrict__ out, int KC) {
  int i = blockIdx.x * 256 + threadIdx.x;
  int total = 16 * KC * 3 * 32 * 64;
  if (i >= total) return;
  int k0  = i & 7;          // element within 16B granule
  int k8s = (i >> 3) & 7;   // stored granule index
  int n   = (i >> 6) & 31;
  int t   = i >> 11;        // (nb*KC + kc)*3 + g
  int g   = t % 3;
  int t2  = t / 3;
  int kc  = t2 % KC;
  int nb  = t2 / KC;
  int k8  = k8s ^ (n & 7);  // logical granule
  int row = g * 512 + nb * 32 + n;
  int kg  = kc * 64 + k8 * 8 + k0;
  float v = (kg < 512) ? Wa[(size_t)row * 512 + kg] : Wb[(size_t)row * 512 + kg - 512];
  out[i] = (_Float16)v;
}

// bias combine: [0]=b_ih_r+b_hh_r, [1]=b_ih_z+b_hh_z, [2]=b_ih_n, [3]=b_hh_n  (each 512)
__global__ void pack_bias(const float* __restrict__ bih, const float* __restrict__ bhh,
                          float* __restrict__ out) {
  int j = blockIdx.x * 256 + threadIdx.x;
  if (j >= 512) return;
  out[j]        = bih[j]        + bhh[j];
  out[512 + j]  = bih[512 + j]  + bhh[512 + j];
  out[1024 + j] = bih[1024 + j];
  out[1536 + j] = bhh[1024 + j];
}

// x-weights for layer0 (K=3): out[j*9 + g*3 + k] = W_ih[(g*512+j)*3 + k]
__global__ void pack_wx(const float* __restrict__ Wih, float* __restrict__ out) {
  int i = blockIdx.x * 256 + threadIdx.x;
  if (i >= 512 * 9) return;
  int j = i / 9, q = i % 9, g = q / 3, k = q % 3;
  out[i] = Wih[(size_t)(g * 512 + j) * 3 + k];
}

// ---------------- fused GRU layer-step GEMM: A-in-regs + B ring-3 + counted vmcnt ----------------
// Block: 256m x 32n, 4 waves; wave w rows w*64..w*64+63 (mt4 x nt2, 128 acc f32 L1 / 96 L0).
// Per kc: issue stage B(s+1) [3 gl2lds] + loadA(s+1)->regs [8 dwordx4 from chunked layout];
// s_waitcnt vmcnt(11) (tile-s loads, issued one kc earlier, landed; tile-s+1 in flight);
// ONE raw s_barrier; compute: 12 B ds_read_b128 + 48 MFMA (A from regs). No drain in loop body.
// Grid: flat 2048; XCD-aware remap (16 col-blocks of a row-block land on one XCD, adjacent in time).
template <int KC, bool L0>
__launch_bounds__(256, 2)
__global__ void gru_step(const _Float16* __restrict__ Bp,     // packed weights [16][KC][3][32][64] (swizzled)
                         const _Float16* __restrict__ Alo,    // fp16 A chunks, k<512 (L0: old state; L1: layer0 out)
                         const _Float16* __restrict__ Ahi,    // fp16 A chunks, k>=512 (L1: old state)
                         _Float16* __restrict__ hnew16,       // fp16 new state (chunked)
                         const float* __restrict__ bias,      // [4*512]
                         const float* __restrict__ Wx,        // [512*9] (L0) or null
                         const float* __restrict__ xin,       // x row base (L0) or null
                         int xstride) {
  __shared__ alignas(16) _Float16 sB3[3][3 * BN * BK];    // 3 x 12KB ring (B only)

  const int tid  = threadIdx.x;
  const int wave = tid >> 6;
  const int lane = tid & 63;
  const int quad = lane >> 4;
  const int l15  = lane & 15;
  const int L  = blockIdx.x;              // 0..2047
  const int c  = L & 7;
  const int q  = L >> 3;                  // 0..255
  const int cb = q & 15;                  // 0..15
  const int rb = (c << 4) | (q >> 4);     // 0..127
  const int row0 = rb * BM;
  const int col0 = cb * BN;

  f4 acc_r[4][2]  = {};
  f4 acc_z[4][2]  = {};
  f4 acc_n0[4][2] = {};   // L1: i_n (kc<8); L0 unused (DCE'd)
  f4 acc_n1[4][2] = {};   // h_n

  const _Float16* Bblk = Bp + (size_t)cb * KC * (3 * BN * BK);

  // stage B K-tile kcs into ring slot dst (12KB, 3 gl2lds/wave; swizzle pre-baked by pack_w)
  auto stageB = [&](int kcs, _Float16* dst) {
    const _Float16* Bsrc = Bblk + (size_t)kcs * (3 * BN * BK);
#pragma unroll
    for (int i = 0; i < 3; ++i) {
      int off = wave * 192 + i * 64;
      gl2lds16(Bsrc + (size_t)(off + lane) * 8, dst + (size_t)off * 8);  // HW adds lane*16B at dest
    }
  };
  // load A K-tile kcs into regs from CHUNKED layout: tile kc covers chunks c0=(kc&7)*2 and c0+1.
  // tgt[mt*2+sk] = A[chunk c0+sk][row0+wave*64+mt*16+l15][quad*8 .. +7]
  auto loadA = [&](int kcs, h8 (&tgt)[8]) {
    const _Float16* Asrc = (KC == 16 && kcs >= 8) ? Ahi : Alo;
    const int c0 = (kcs & 7) * 2;
#pragma unroll
    for (int mt = 0; mt < 4; ++mt) {
      int row = row0 + wave * 64 + mt * 16 + l15;
      tgt[mt * 2 + 0] = *(const h8*)(Asrc + ((size_t)(c0    ) * BATCH + row) * 32 + quad * 8);
      tgt[mt * 2 + 1] = *(const h8*)(Asrc + ((size_t)(c0 + 1) * BATCH + row) * 32 + quad * 8);
    }
  };
  // one K-tile of MFMAs: A from regs, B from ring slot
  auto compute = [&](int s, const _Float16* sBc, const h8 (&A)[8]) {
#pragma unroll
    for (int sk = 0; sk < 2; ++sk) {
      const int sw = ((sk * 4 + quad) ^ (l15 & 7)) * 8;   // granule swizzle key
#pragma unroll
      for (int nt = 0; nt < 2; ++nt) {
        const int nrow = nt * 16 + l15;
        h8 br = *(const h8*)&sBc[(0 * BN + nrow) * BK + sw];
        h8 bz = *(const h8*)&sBc[(1 * BN + nrow) * BK + sw];
        h8 bn = *(const h8*)&sBc[(2 * BN + nrow) * BK + sw];
#pragma unroll
        for (int mt = 0; mt < 4; ++mt) {
          acc_r[mt][nt] = __builtin_amdgcn_mfma_f32_16x16x32_f16(A[mt * 2 + sk], br, acc_r[mt][nt], 0, 0, 0);
          acc_z[mt][nt] = __builtin_amdgcn_mfma_f32_16x16x32_f16(A[mt * 2 + sk], bz, acc_z[mt][nt], 0, 0, 0);
          if (L0 || s >= 8)
            acc_n1[mt][nt] = __builtin_amdgcn_mfma_f32_16x16x32_f16(A[mt * 2 + sk], bn, acc_n1[mt][nt], 0, 0, 0);
          else
            acc_n0[mt][nt] = __builtin_amdgcn_mfma_f32_16x16x32_f16(A[mt * 2 + sk], bn, acc_n0[mt][nt], 0, 0, 0);
        }
      }
    }
  };

  h8 Aa[8], Ab[8];                 // statically-named A ping-pong (rule: no dynamic reg indexing)
  stageB(0, sB3[0]); loadA(0, Aa); // prologue: tile 0 in flight (11 vmem ops)

  int cs = 0;                      // ring slot of tile s
  for (int s = 0; s < KC; s += 2) {   // KC even (8 or 16)
    const int s1 = (cs == 2) ? 0 : cs + 1;
    const int s2 = (s1 == 2) ? 0 : s1 + 1;
    // ---- even kc s: prefetch tile s+1 -> slot s1 / regs Ab; compute tile s from slot cs / Aa ----
    stageB(s + 1, sB3[s1]); loadA(s + 1, Ab);
    asm volatile("s_waitcnt vmcnt(11)" ::: "memory");   // tile-s loads landed; s+1 stays in flight
    __builtin_amdgcn_s_barrier();                        // all waves' B(s) visible; slot s2 free
    __builtin_amdgcn_sched_barrier(0);                   // no ds_read hoisted above the barrier
    compute(s, sB3[cs], Aa);
    // ---- odd kc s+1: prefetch tile s+2 -> slot s2 / regs Aa; compute tile s+1 from slot s1 / Ab ----
    if (s + 2 < KC) {
      stageB(s + 2, sB3[s2]); loadA(s + 2, Aa);
      asm volatile("s_waitcnt vmcnt(11)" ::: "memory");
    } else {
      asm volatile("s_waitcnt vmcnt(0)" ::: "memory");   // tail: tile KC-1 loads had a full kc to land
    }
    __builtin_amdgcn_s_barrier();
    __builtin_amdgcn_sched_barrier(0);
    compute(s + 1, sB3[s1], Ab);
    cs = s2;
  }

  // ---------------- fused epilogue: gates + state update (chunked, full-line writes) ----------------
  const _Float16* hold16 = L0 ? Alo : Ahi;
  float bR[2], bZ[2], bI[2], bH[2];
  float wx[2][9];
#pragma unroll
  for (int nt = 0; nt < 2; ++nt) {
    int j = col0 + nt * 16 + l15;
    bR[nt] = bias[j];
    bZ[nt] = bias[512 + j];
    bI[nt] = bias[1024 + j];
    bH[nt] = bias[1536 + j];
    if constexpr (L0) {
#pragma unroll
      for (int q2 = 0; q2 < 9; ++q2) wx[nt][q2] = Wx[j * 9 + q2];
    }
  }
#pragma unroll
  for (int mt = 0; mt < 4; ++mt) {
    // xv scoped per-mt: keeps register peak down
    float xv[4][3];
    if constexpr (L0) {
#pragma unroll
      for (int r = 0; r < 4; ++r) {
        int b = row0 + wave * 64 + mt * 16 + quad * 4 + r;
        const float* xp = xin + (size_t)b * xstride;
        xv[r][0] = xp[0]; xv[r][1] = xp[1]; xv[r][2] = xp[2];
      }
    }
#pragma unroll
    for (int r = 0; r < 4; ++r) {
      int b = row0 + wave * 64 + mt * 16 + quad * 4 + r;   // C/D: row = quad*4+reg
#pragma unroll
      for (int nt = 0; nt < 2; ++nt) {
        int jj = nt * 16 + l15;                             // col within this block's chunk cb
        size_t idx = ((size_t)cb * BATCH + b) * 32 + jj;    // chunked: contiguous per block
        float rr = acc_r[mt][nt][r] + bR[nt];
        float zz = acc_z[mt][nt][r] + bZ[nt];
        float hn = acc_n1[mt][nt][r] + bH[nt];
        float in_;
        if constexpr (L0) {
          const float* w = wx[nt];
          rr += xv[r][0] * w[0] + xv[r][1] * w[1] + xv[r][2] * w[2];
          zz += xv[r][0] * w[3] + xv[r][1] * w[4] + xv[r][2] * w[5];
          in_ = bI[nt] + xv[r][0] * w[6] + xv[r][1] * w[7] + xv[r][2] * w[8];
        } else {
          in_ = acc_n0[mt][nt][r] + bI[nt];
        }
        float rg = sigm(rr);
        float zg = sigm(zz);
        float ng = tanhfast(in_ + rg * hn);
        float hp = (float)hold16[idx];
        float hv = (1.f - zg) * ng + zg * hp;
        hnew16[idx] = (_Float16)hv;
      }
    }
  }
}

// ---------------- fc head: pred[b,d] = h[b,:] . fcW[d,:] + fcb[d]  (chunked h) ----------------
__global__ __launch_bounds__(256) void fc_kernel(const _Float16* __restrict__ h,
                                                 const float* __restrict__ W,
                                                 const float* __restrict__ bfc,
                                                 float* __restrict__ out) {  // out = d_out + t*3
  int wave = threadIdx.x >> 6, lane = threadIdx.x & 63;
  int b = blockIdx.x * 4 + wave;
  // lane covers k = lane*8..lane*8+7 -> chunk = lane>>2, offset (lane&3)*8
  h8 a0 = *(const h8*)(h + ((size_t)(lane >> 2) * BATCH + b) * 32 + (lane & 3) * 8);
  float s[3];
#pragma unroll
  for (int d = 0; d < 3; ++d) {
    const float4* wp = (const float4*)(W + d * 512);
    float4 w0 = wp[lane * 2], w1 = wp[lane * 2 + 1];
    s[d] = (float)a0[0] * w0.x + (float)a0[1] * w0.y + (float)a0[2] * w0.z + (float)a0[3] * w0.w
         + (float)a0[4] * w1.x + (float)a0[5] * w1.y + (float)a0[6] * w1.z + (float)a0[7] * w1.w;
  }
#pragma unroll
  for (int d = 0; d < 3; ++d)
#pragma unroll
    for (int off = 32; off > 0; off >>= 1) s[d] += __shfl_xor(s[d], off, 64);
  if (lane == 0) {
    out[(size_t)b * 90 + 0] = s[0] + bfc[0];
    out[(size_t)b * 90 + 1] = s[1] + bfc[1];
    out[(size_t)b * 90 + 2] = s[2] + bfc[2];
  }
}

extern "C" void kernel_launch(void* const* d_in, const int* in_sizes, int n_in,
                              void* d_out, int out_size, void* d_ws, size_t ws_size,
                              hipStream_t stream) {
  (void)in_sizes; (void)n_in; (void)out_size; (void)ws_size;
  const float* x_input = (const float*)d_in[0];
  const float* eWih0 = (const float*)d_in[2];
  const float* eWhh0 = (const float*)d_in[3];
  const float* ebih0 = (const float*)d_in[4];
  const float* ebhh0 = (const float*)d_in[5];
  const float* eWih1 = (const float*)d_in[6];
  const float* eWhh1 = (const float*)d_in[7];
  const float* ebih1 = (const float*)d_in[8];
  const float* ebhh1 = (const float*)d_in[9];
  const float* dWih0 = (const float*)d_in[10];
  const float* dWhh0 = (const float*)d_in[11];
  const float* dbih0 = (const float*)d_in[12];
  const float* dbhh0 = (const float*)d_in[13];
  const float* dWih1 = (const float*)d_in[14];
  const float* dWhh1 = (const float*)d_in[15];
  const float* dbih1 = (const float*)d_in[16];
  const float* dbhh1 = (const float*)d_in[17];
  const float* fcW   = (const float*)d_in[18];
  const float* fcb   = (const float*)d_in[19];
  float* out = (float*)d_out;

  char* ws = (char*)d_ws;
  const size_t S16 = (size_t)BATCH * HID * 2;   // 32MB
  _Float16* h0h[2] = {(_Float16*)(ws),            (_Float16*)(ws + S16)};
  _Float16* h1h[2] = {(_Float16*)(ws + 2 * S16),  (_Float16*)(ws + 3 * S16)};
  char* p = ws + 4 * S16;                        // 128MB
  const size_t W8  = (size_t)16 * 8  * 3 * 32 * 64 * 2;  // 1.5MB (KC=8)
  const size_t W16 = (size_t)16 * 16 * 3 * 32 * 64 * 2;  // 3MB (KC=16)
  _Float16* pkE0 = (_Float16*)p; p += W8;
  _Float16* pkE1 = (_Float16*)p; p += W16;
  _Float16* pkD0 = (_Float16*)p; p += W8;
  _Float16* pkD1 = (_Float16*)p; p += W16;
  float* bE0 = (float*)p; p += 2048 * 4;
  float* bE1 = (float*)p; p += 2048 * 4;
  float* bD0 = (float*)p; p += 2048 * 4;
  float* bD1 = (float*)p; p += 2048 * 4;
  float* wxE = (float*)p; p += 512 * 9 * 4;
  float* wxD = (float*)p; p += 512 * 9 * 4;
  // total ws usage: 128MB + ~9.1MB

  // repack weights/biases (every call; ws is re-poisoned by harness)
  pack_w<<<dim3(3072), 256, 0, stream>>>(eWhh0, eWhh0, pkE0, 8);
  pack_w<<<dim3(6144), 256, 0, stream>>>(eWih1, eWhh1, pkE1, 16);
  pack_w<<<dim3(3072), 256, 0, stream>>>(dWhh0, dWhh0, pkD0, 8);
  pack_w<<<dim3(6144), 256, 0, stream>>>(dWih1, dWhh1, pkD1, 16);
  pack_bias<<<2, 256, 0, stream>>>(ebih0, ebhh0, bE0);
  pack_bias<<<2, 256, 0, stream>>>(ebih1, ebhh1, bE1);
  pack_bias<<<2, 256, 0, stream>>>(dbih0, dbhh0, bD0);
  pack_bias<<<2, 256, 0, stream>>>(dbih1, dbhh1, bD1);
  pack_wx<<<18, 256, 0, stream>>>(eWih0, wxE);
  pack_wx<<<18, 256, 0, stream>>>(dWih0, wxD);

  // zero-init fp16 states (ping index 0)
  {
    int n4 = (int)(S16 / 16);
    zero_fill<<<(n4 + 255) / 256, 256, 0, stream>>>((float4*)h0h[0], n4);
    zero_fill<<<(n4 + 255) / 256, 256, 0, stream>>>((float4*)h1h[0], n4);
  }

  dim3 grid(2048), blk(256);
  int p0 = 0, p1 = 0;
  // encoder
  for (int t = 0; t < T_HIST; ++t) {
    gru_step<8, true><<<grid, blk, 0, stream>>>(pkE0, h0h[p0], nullptr,
                                                h0h[1 - p0], bE0, wxE,
                                                x_input + (size_t)t * 3, 150);
    p0 ^= 1;
    gru_step<16, false><<<grid, blk, 0, stream>>>(pkE1, h0h[p0], h1h[p1],
                                                  h1h[1 - p1], bE1, nullptr, nullptr, 0);
    p1 ^= 1;
  }
  // autoregressive decoder
  for (int t = 0; t < FUT; ++t) {
    const float* xp; int xs;
    if (t == 0) { xp = x_input + (size_t)49 * 3; xs = 150; }
    else        { xp = out + (size_t)(t - 1) * 3; xs = 90; }
    gru_step<8, true><<<grid, blk, 0, stream>>>(pkD0, h0h[p0], nullptr,
                                                h0h[1 - p0], bD0, wxD, xp, xs);
    p0 ^= 1;
    gru_step<16, false><<<grid, blk, 0, stream>>>(pkD1, h0h[p0], h1h[p1],
                                                  h1h[1 - p1], bD1, nullptr, nullptr, 0);
    p1 ^= 1;
    fc_kernel<<<8192, 256, 0, stream>>>(h1h[p1], fcW, fcb, out + (size_t)t * 3);
  }
}